// Round 13
// baseline (66.405 us; speedup 1.0000x reference)
//
#include <hip/hip_runtime.h>
#include <hip/hip_fp16.h>

#define W 256
#define NA 180
#define SPLIT 4
#define ROWBYTES 580       // 290 halfs = 145 words; odd word stride -> axis walks spread across all 32 banks
#define HROWS 130          // local rows per half-image block (75,400 B -> 2 blocks/CU)

// half h=0: biased rows 0..129 (guard row 0 + pixels 0..128)
// half h=1: biased rows 129..258 (pixels 128..255 + guard rows 257,258)
// cols: halfs 0,1 and 258,259 are guards; data cols 2..257 (pixel x + 2)

__global__ __launch_bounds__(1024, 8) void radon_kernel(
    const float* __restrict__ x, const int* __restrict__ index_p,
    float* __restrict__ out)
{
    __shared__ __half simg[HROWS * 290];   // 75,400 B

    const int a = blockIdx.x;        // angle
    const int n = blockIdx.y;        // batch
    const int h = blockIdx.z;        // image half
    const int tid = threadIdx.x;
    const int c = tid & (W - 1);     // column
    const int s = tid >> 8;          // r-chunk (wave-uniform)

    const float* __restrict__ img = x + (size_t)n * W * W;

    // ---- guard zero-fill (cells disjoint from staged data) ----
    {
        unsigned* wp = (unsigned*)simg;
        if (tid < 260) {                        // col guards, all 130 local rows
            const int row = tid >> 1;
            const int w = (tid & 1) ? 129 : 0;
            wp[row * 145 + w] = 0u;
        } else {
            const int i = tid - 260;
            if (h == 0) {
                if (i < 145) wp[i] = 0u;        // local row 0 (biased 0)
            } else {
                if (i < 290) {                  // local rows 128,129 (biased 257,258)
                    const int row = 128 + (i >= 145);
                    const int w = (i >= 145) ? (i - 145) : i;
                    wp[row * 145 + w] = 0u;
                }
            }
        }
    }

    // ---- stage this half's pixel rows -> LDS fp16 ----
    {
        const int ps = h ? 128 : 0;             // first pixel row
        const int nrows = h ? 128 : 129;
        const int lbias = h ? -128 : 1;         // local row = pixel row + lbias
        const float4* img4 = (const float4*)(img + ps * W);
        const int ngroups = nrows * 64;         // float4 groups in region
        for (int g = tid; g < ngroups; g += 1024) {
            const int rr = g >> 6;              // pixel row - ps
            const int m = g & 63;
            const float4 v = img4[g];
            const __half2 h01 = __floats2half2_rn(v.x, v.y);
            const __half2 h23 = __floats2half2_rn(v.z, v.w);
            char* base = (char*)simg + (rr + ps + lbias) * ROWBYTES + 8 * m + 4;
            *(unsigned*)(base)     = *(const unsigned*)&h01;
            *(unsigned*)(base + 4) = *(const unsigned*)&h23;
        }
    }
    __syncthreads();

    const int index = *index_p;
    const int seg[6] = {1, 26, 51, 77, 102, 128};
    const int t0 = seg[4 - index];
    const int t1 = seg[4 - index + 1];

    float sa, ca;
    sincosf((float)a * 0.017453292519943295f, &sa, &ca);

    const float xc = ((2.0f * (float)c + 1.0f) * (1.0f / (float)W)) - 1.0f;
    const float bx  = fmaf(128.0f * ca, xc, 127.5f + 2.0f);   // +2 x bias
    const float byg = fmaf(-128.0f * sa, xc, 127.5f + 1.0f);  // +1 y bias (GLOBAL biased)
    const float byh = byg - 129.0f * (float)h;                // local-row base
    const float yup = h ? 128.0f : 257.0f;                    // local upper clamp

    const int r1lo = 128 - t1, r1hi = 127 + t1;
    const int r0lo = 128 - t0, r0hi = 127 + t0;

    // ---- exact r-partition: this half owns r's whose tap row-pair lies in it ----
    int lo, hi;
    {
        float t = 127.5f + (129.0f - byg) / ca;               // may be huge/inf
        t = __builtin_amdgcn_fmed3f(t, (float)(r1lo - 1), (float)(r1hi + 1));
        int rsp = (int)t;
#define PRED(r) (__builtin_amdgcn_fmed3f(fmaf(ca, (float)(r) - 127.5f, byg), 0.0f, 257.0f) < 129.0f)
        if (ca >= 0.0f) {                                     // PRED true on prefix
            rsp = min(max(rsp, r1lo - 1), r1hi);
            while (rsp < r1hi && PRED(rsp + 1)) ++rsp;        // rsp = last true
            while (rsp >= r1lo && !PRED(rsp)) --rsp;
            lo = h ? rsp + 1 : r1lo;
            hi = h ? r1hi : rsp;
        } else {                                              // PRED true on suffix
            rsp = min(max(rsp, r1lo), r1hi + 1);
            while (rsp > r1lo && PRED(rsp - 1)) --rsp;        // rsp = first true
            while (rsp <= r1hi && !PRED(rsp)) ++rsp;
            lo = h ? r1lo : rsp;
            hi = h ? rsp - 1 : r1hi;
        }
#undef PRED
    }

    int rs, re;
    {
        const int len = hi - lo + 1;
        if (len > 0) {
            const int chunk = (len + SPLIT - 1) / SPLIT;
            rs = lo + s * chunk;
            re = min(rs + chunk, lo + len);
        } else { rs = 0; re = 0; }
    }

    const char* S = (const char*)simg;

#define TAP_BODY                                                              \
        float ix = fmaf(sa, rf, bx);                                          \
        float iy = fmaf(ca, rf, byh);                                         \
        ix = __builtin_amdgcn_fmed3f(ix, 1.0f, 258.0f);                       \
        iy = __builtin_amdgcn_fmed3f(iy, 0.0f, yup);                          \
        const float wx = __builtin_amdgcn_fractf(ix);                         \
        const float wy = __builtin_amdgcn_fractf(iy);                         \
        const int x0 = (int)ix;                                               \
        const int y0 = (int)iy;                                               \
        const int sh = (x0 & 1) << 4;                                         \
        const char* p = S + (y0 * ROWBYTES + (x0 >> 1) * 4);                  \
        const unsigned A0 = *(const unsigned*)(p);                            \
        const unsigned A1 = *(const unsigned*)(p + ROWBYTES);                 \
        const unsigned B0 = *(const unsigned*)(p + 4);                        \
        const unsigned B1 = *(const unsigned*)(p + ROWBYTES + 4);             \
        const unsigned q0 = (unsigned)(((((unsigned long long)B0) << 32) | A0) >> sh); \
        const unsigned q1 = (unsigned)(((((unsigned long long)B1) << 32) | A1) >> sh); \
        const __half2 h0v = *(const __half2*)&q0;                             \
        const __half2 h1v = *(const __half2*)&q1;                             \
        const float v00 = __low2float(h0v);                                   \
        const float v01 = __high2float(h0v);                                  \
        const float v10 = __low2float(h1v);                                   \
        const float v11 = __high2float(h1v);                                  \
        const float top = fmaf(wx, v01 - v00, v00);                           \
        const float bot = fmaf(wx, v11 - v10, v10);                           \
        const float val = fmaf(wy, bot - top, top);

    float sumA = 0.0f, sumB = 0.0f, sumC = 0.0f;
    {   // segment A: [rs, min(re, r0lo)) -> outer only
        const int e = min(re, r0lo);
        float rf = (float)rs - 127.5f;
        #pragma unroll 4
        for (int r = rs; r < e; ++r, rf += 1.0f) { TAP_BODY sumA += val; }
    }
    {   // segment B: [max(rs, r0lo), min(re, r0hi+1)) -> both masks
        const int b = max(rs, r0lo);
        const int e = min(re, r0hi + 1);
        float rf = (float)b - 127.5f;
        #pragma unroll 4
        for (int r = b; r < e; ++r, rf += 1.0f) { TAP_BODY sumB += val; }
    }
    {   // segment C: [max(rs, r0hi+1), re) -> outer only
        const int b = max(rs, r0hi + 1);
        float rf = (float)b - 127.5f;
        #pragma unroll 4
        for (int r = b; r < re; ++r, rf += 1.0f) { TAP_BODY sumC += val; }
    }
#undef TAP_BODY

    const float sum0 = sumB;
    const float sum1 = sumA + sumB + sumC;

    // ---- block reduce; simg reused as scratch (tap reads done) ----
    __syncthreads();
    float* red = (float*)simg;                 // 8 KB of 75 KB
    red[(0 * SPLIT + s) * W + c] = sum0;
    red[(1 * SPLIT + s) * W + c] = sum1;
    __syncthreads();

    if (s == 0) {
        const float acc0 = red[0 * W + c] + red[1 * W + c] + red[2 * W + c] + red[3 * W + c];
        const float* r1p = red + SPLIT * W;
        const float acc1 = r1p[0 * W + c] + r1p[1 * W + c] + r1p[2 * W + c] + r1p[3 * W + c];
        // exactly two contributions per location (h=0,1); float add commutes -> deterministic
        atomicAdd(out + (((size_t)n * 2 + 0) * W + c) * NA + a, acc0 * (1.0f / (float)(2 * t0)));
        atomicAdd(out + (((size_t)n * 2 + 1) * W + c) * NA + a, acc1 * (1.0f / (float)(2 * t1)));
    }
}

extern "C" void kernel_launch(void* const* d_in, const int* in_sizes, int n_in,
                              void* d_out, int out_size, void* d_ws, size_t ws_size,
                              hipStream_t stream) {
    const float* x = (const float*)d_in[0];
    const int* index_p = (const int*)d_in[1];
    float* out = (float*)d_out;
    const int N = in_sizes[0] / (W * W); // 4

    hipMemsetAsync(d_out, 0, (size_t)out_size * sizeof(float), stream);

    dim3 grid(NA, N, 2);
    radon_kernel<<<grid, 1024, 0, stream>>>(x, index_p, out);
}

// Round 15
// 61.236 us; speedup vs baseline: 1.0844x; 1.0844x over previous
//
#include <hip/hip_runtime.h>
#include <hip/hip_fp16.h>

#define W 256
#define NA 180
#define SPLIT 4
#define RWORDS 145          // 32-bit words per padded row (odd -> bank-spread)
#define LROWS 131           // local rows: guard, 128 pixel rows, guard, guard
#define SWORDS (LROWS * RWORDS)   // 18,995 words = 75,980 B -> 2 blocks/CU

// half h owns pixel rows [h*128, h*128+127] at local rows 1..128.
// local rows 0,129,130 are zero guards; words 0 and 129 of each row are col guards.
// data: pixel x at halfs x+2 (words 1..128).

__global__ __launch_bounds__(1024, 8) void radon_kernel(
    const float* __restrict__ x, const int* __restrict__ index_p,
    float* __restrict__ out)
{
    __shared__ unsigned sw[SWORDS];

    const int a = blockIdx.x;        // angle
    const int n = blockIdx.y;        // batch
    const int h = blockIdx.z;        // image half (row-wise)
    const int tid = threadIdx.x;
    const int c = tid & (W - 1);
    const int s = tid >> 8;          // r-chunk (wave-uniform)

    // ---- guard zero-fill (disjoint words from staged data) ----
    if (tid < 435) {                 // local rows 0,129,130 fully zero
        const int rr = tid / 145;
        const int w = tid - rr * 145;
        const int row = (rr == 0) ? 0 : (128 + rr);
        sw[row * RWORDS + w] = 0u;
    } else if (tid < 691) {          // col guard words 0,129 for rows 1..128
        const int i = tid - 435;
        const int row = 1 + (i >> 1);
        const int w = (i & 1) ? 129 : 0;
        sw[row * RWORDS + w] = 0u;
    }

    // ---- stage this half's 128 pixel rows -> LDS fp16 ----
    {
        const float4* img4 = (const float4*)(x + (size_t)n * W * W + h * 128 * W);
        #pragma unroll
        for (int k = 0; k < 8; ++k) {
            const int g = k * 1024 + tid;      // 8192 float4 groups
            const int lr = (g >> 6) + 1;       // local row 1..128
            const int m = g & 63;
            const float4 v = img4[g];
            const __half2 h01 = __floats2half2_rn(v.x, v.y);
            const __half2 h23 = __floats2half2_rn(v.z, v.w);
            sw[lr * RWORDS + 2 * m + 1] = *(const unsigned*)&h01;
            sw[lr * RWORDS + 2 * m + 2] = *(const unsigned*)&h23;
        }
    }
    __syncthreads();

    const int index = *index_p;
    const int seg[6] = {1, 26, 51, 77, 102, 128};
    const int t0 = seg[4 - index];
    const int t1 = seg[4 - index + 1];

    float sa, ca;
    sincosf((float)a * 0.017453292519943295f, &sa, &ca);

    const float xc = ((2.0f * (float)c + 1.0f) * (1.0f / (float)W)) - 1.0f;
    const float bx  = fmaf(128.0f * ca, xc, 129.5f);   // +2 x bias
    const float byg = fmaf(-128.0f * sa, xc, 128.5f);  // +1 y bias (global biased)
    const float byh = byg - 128.0f * (float)h;         // local row coordinate base

    const int r1lo = 128 - t1, r1hi = 127 + t1;
    const int r0lo = 128 - t0, r0hi = 127 + t0;

    // ---- wave-uniform r-interval (overshoot-safe: guards absorb to 0) ----
    // iy_local(r) = ca*(r-127.5) + byh ; nonzero taps need iy_local in (-1,130).
    int rs = 0, re = 0;
    {
        const float inv = 1.0f / ca;                 // ca never exactly 0 (float degrees)
        const float b0 = fmaf(-1.0f - byh, inv, 127.5f);   // r at iy=-1
        const float b1 = fmaf(130.0f - byh, inv, 127.5f);  // r at iy=130
        float lo_f = fminf(b0, b1), hi_f = fmaxf(b0, b1);
        lo_f = __builtin_amdgcn_fmed3f(lo_f, -1.0f, 400.0f);
        hi_f = __builtin_amdgcn_fmed3f(hi_f, -1.0f, 400.0f);
        int wl = max((int)floorf(lo_f), r1lo);
        int wh = min((int)ceilf(hi_f), r1hi);
        // bounds monotone in c -> wave extremes at end lanes
        const int l0 = __shfl(wl, 0), l63 = __shfl(wl, 63);
        const int u0 = __shfl(wh, 0), u63 = __shfl(wh, 63);
        wl = min(l0, l63);
        wh = max(u0, u63);
        const int len = wh - wl + 1;
        if (len > 0) {
            const int chunk = (len + SPLIT - 1) / SPLIT;
            rs = wl + s * chunk;
            re = min(rs + chunk, wl + len);
        }
    }

#define TAP_BODY                                                              \
        float ixf = fmaf(sa, rf, bx);                                         \
        float iyf = fmaf(ca, rf, byh);                                        \
        ixf = __builtin_amdgcn_fmed3f(ixf, 1.0f, 258.0f);                     \
        iyf = __builtin_amdgcn_fmed3f(iyf, 0.0f, 129.0f);                     \
        const float wx = __builtin_amdgcn_fractf(ixf);                        \
        const float wy = __builtin_amdgcn_fractf(iyf);                        \
        const int x0 = (int)ixf;                                              \
        const int y0 = (int)iyf;                                              \
        const int wi = y0 * RWORDS + (x0 >> 1);                               \
        const unsigned A0 = sw[wi];                                           \
        const unsigned B0 = sw[wi + 1];                                       \
        const unsigned A1 = sw[wi + RWORDS];                                  \
        const unsigned B1 = sw[wi + RWORDS + 1];                              \
        const int sh = (x0 & 1) << 4;                                         \
        const unsigned q0 = (unsigned)(((((unsigned long long)B0) << 32) | A0) >> sh); \
        const unsigned q1 = (unsigned)(((((unsigned long long)B1) << 32) | A1) >> sh); \
        const __half2 h0v = *(const __half2*)&q0;                             \
        const __half2 h1v = *(const __half2*)&q1;                             \
        const float v00 = __low2float(h0v);                                   \
        const float v01 = __high2float(h0v);                                  \
        const float v10 = __low2float(h1v);                                   \
        const float v11 = __high2float(h1v);                                  \
        const float top = fmaf(wx, v01 - v00, v00);                           \
        const float bot = fmaf(wx, v11 - v10, v10);                           \
        const float val = fmaf(wy, bot - top, top);

    float sumA = 0.0f, sumB = 0.0f, sumC = 0.0f;
    {   // segment A: [rs, min(re, r0lo)) -> outer mask only
        const int e = min(re, r0lo);
        float rf = (float)rs - 127.5f;
        #pragma unroll 4
        for (int r = rs; r < e; ++r, rf += 1.0f) { TAP_BODY sumA += val; }
    }
    {   // segment B: [max(rs, r0lo), min(re, r0hi+1)) -> both masks
        const int b = max(rs, r0lo);
        const int e = min(re, r0hi + 1);
        float rf = (float)b - 127.5f;
        #pragma unroll 4
        for (int r = b; r < e; ++r, rf += 1.0f) { TAP_BODY sumB += val; }
    }
    {   // segment C: [max(rs, r0hi+1), re) -> outer mask only
        const int b = max(rs, r0hi + 1);
        float rf = (float)b - 127.5f;
        #pragma unroll 4
        for (int r = b; r < re; ++r, rf += 1.0f) { TAP_BODY sumC += val; }
    }
#undef TAP_BODY

    const float sum0 = sumB;
    const float sum1 = sumA + sumB + sumC;

    // ---- block reduce; alias sw as scratch (tap reads done) ----
    __syncthreads();
    float* red = (float*)sw;                   // 8 KB of 76 KB
    red[(0 * SPLIT + s) * W + c] = sum0;
    red[(1 * SPLIT + s) * W + c] = sum1;
    __syncthreads();

    if (s == 0) {
        const float acc0 = red[0 * W + c] + red[1 * W + c] + red[2 * W + c] + red[3 * W + c];
        const float* r1p = red + SPLIT * W;
        const float acc1 = r1p[0 * W + c] + r1p[1 * W + c] + r1p[2 * W + c] + r1p[3 * W + c];
        // exactly two contributors (h=0,1); float add commutes bitwise -> deterministic
        atomicAdd(out + (((size_t)n * 2 + 0) * W + c) * NA + a, acc0 * (1.0f / (float)(2 * t0)));
        atomicAdd(out + (((size_t)n * 2 + 1) * W + c) * NA + a, acc1 * (1.0f / (float)(2 * t1)));
    }
}

extern "C" void kernel_launch(void* const* d_in, const int* in_sizes, int n_in,
                              void* d_out, int out_size, void* d_ws, size_t ws_size,
                              hipStream_t stream) {
    const float* x = (const float*)d_in[0];
    const int* index_p = (const int*)d_in[1];
    float* out = (float*)d_out;
    const int N = in_sizes[0] / (W * W); // 4

    hipMemsetAsync(d_out, 0, (size_t)out_size * sizeof(float), stream);

    dim3 grid(NA, N, 2);
    radon_kernel<<<grid, 1024, 0, stream>>>(x, index_p, out);
}

// Round 16
// 50.083 us; speedup vs baseline: 1.3259x; 1.2227x over previous
//
#include <hip/hip_runtime.h>
#include <hip/hip_fp16.h>

#define W 256
#define NA 180
#define SPLIT 4
#define ROWBYTES 580          // 290 halfs = 145 words; odd word stride -> axis walks spread over banks
#define ROWS 259              // data rows 1..256 (pixel y + 1); data cols (halfs) 2..257 (pixel x + 2)

__global__ __launch_bounds__(1024) void radon_kernel(
    const float* __restrict__ x, const int* __restrict__ index_p,
    float* __restrict__ out)
{
    __shared__ __half simg[ROWS * 290];   // 150,220 B

    const int a = blockIdx.x;        // angle 0..179
    const int n = blockIdx.y;        // batch
    const int tid = threadIdx.x;
    const int c = tid & (W - 1);     // column 0..255
    const int s = tid >> 8;          // r-chunk 0..3 (wave-uniform)

    const float* __restrict__ img = x + (size_t)n * W * W;

    // ---- guard zero-fill (cells disjoint from staged data -> one barrier total) ----
    {
        unsigned* wp = (unsigned*)simg;
        if (tid < 435) {                       // rows 0,257,258: 3 x 145 words
            const int rr = tid / 145;
            const int w = tid - rr * 145;
            const int row = (rr == 0) ? 0 : (256 + rr);
            wp[row * 145 + w] = 0u;
        } else if (tid < 947) {                // col guard words 0,129 rows 1..256
            const int i = tid - 435;
            const int row = 1 + (i >> 1);
            const int w = (i & 1) ? 129 : 0;
            wp[row * 145 + w] = 0u;
        }
    }

    // ---- stage image -> LDS fp16 ----
    {
        const float4* img4 = (const float4*)img;
        #pragma unroll
        for (int k = 0; k < 16; ++k) {
            const int g = k * 1024 + tid;
            const int row = (g >> 6) + 1;      // 1..256
            const int m = g & 63;
            const float4 v = img4[g];
            const __half2 h01 = __floats2half2_rn(v.x, v.y);
            const __half2 h23 = __floats2half2_rn(v.z, v.w);
            char* base = (char*)simg + row * ROWBYTES + 8 * m + 4;  // halfs 4m+2..
            *(unsigned*)(base)     = *(const unsigned*)&h01;
            *(unsigned*)(base + 4) = *(const unsigned*)&h23;
        }
    }
    __syncthreads();

    const int index = *index_p;
    const int seg[6] = {1, 26, 51, 77, 102, 128};
    const int t0 = seg[4 - index];
    const int t1 = seg[4 - index + 1];

    float sa, ca;
    sincosf((float)a * 0.017453292519943295f, &sa, &ca);

    const float xc = ((2.0f * (float)c + 1.0f) * (1.0f / (float)W)) - 1.0f;
    const float bx = fmaf(128.0f * ca, xc, 127.5f + 2.0f);
    const float by = fmaf(-128.0f * sa, xc, 127.5f + 1.0f);

    const int r1lo = 128 - t1;
    const int r0lo = 128 - t0, r0hi = 127 + t0;
    const int total = 2 * t1;
    const int chunk = (total + SPLIT - 1) / SPLIT;
    const int rs = r1lo + s * chunk;
    const int re = min(rs + chunk, r1lo + total);

    const int len = re - rs;                 // >= 13 for all valid index
    const int w0 = r0hi - r0lo;              // inner-window width-1
    const int base0 = rs - r0lo;             // k + base0 in [0,w0] -> inner mask
    const float rf0 = (float)rs - 127.5f;

    float sum0 = 0.0f, sum1 = 0.0f;

    // ---- software-pipelined tap loop: 2 stages, counted lgkmcnt, asm ds_read2 ----
    float awx, awy; int ash, aad; unsigned long long aqA, aqB;
    float bwx, bwy; int bsh, bad; unsigned long long bqA, bqB;

#define STG(PWX, PWY, PSH, PAD, K) {                                          \
        const int kc = min((K), len - 1);   /* clamp: junk tail, masked */    \
        const float rfk = rf0 + (float)kc;                                    \
        float ixf = fmaf(sa, rfk, bx);                                        \
        float iyf = fmaf(ca, rfk, by);                                        \
        ixf = __builtin_amdgcn_fmed3f(ixf, 1.0f, 258.0f);                     \
        iyf = __builtin_amdgcn_fmed3f(iyf, 0.0f, 257.0f);                     \
        PWX = __builtin_amdgcn_fractf(ixf);                                   \
        PWY = __builtin_amdgcn_fractf(iyf);                                   \
        const int x0 = (int)ixf;                                              \
        const int y0 = (int)iyf;                                              \
        PSH = (x0 & 1) << 4;                                                  \
        PAD = y0 * ROWBYTES + (x0 >> 1) * 4; }

#define ISS(QA, QB, PAD)                                                      \
        asm volatile("ds_read2_b32 %0, %2 offset0:0 offset1:145\n\t"          \
                     "ds_read2_b32 %1, %2 offset0:1 offset1:146"              \
                     : "=&v"(QA), "=&v"(QB) : "v"(PAD));

#define CNS(QA, QB, PWX, PWY, PSH, K) {                                       \
        asm volatile("s_waitcnt lgkmcnt(2)" : "+v"(QA), "+v"(QB));            \
        const unsigned A0 = (unsigned)QA, A1 = (unsigned)(QA >> 32);          \
        const unsigned B0 = (unsigned)QB, B1 = (unsigned)(QB >> 32);          \
        const unsigned q0 = (unsigned)(((((unsigned long long)B0) << 32) | A0) >> PSH); \
        const unsigned q1 = (unsigned)(((((unsigned long long)B1) << 32) | A1) >> PSH); \
        const __half2 h0 = *(const __half2*)&q0;                              \
        const __half2 h1 = *(const __half2*)&q1;                              \
        const float v00 = __low2float(h0), v01 = __high2float(h0);            \
        const float v10 = __low2float(h1), v11 = __high2float(h1);            \
        const float top = fmaf(PWX, v01 - v00, v00);                          \
        const float bot = fmaf(PWX, v11 - v10, v10);                          \
        float val = fmaf(PWY, bot - top, top);                                \
        if ((K) >= len) val = 0.0f;          /* junk tail */                  \
        sum1 += val;                                                          \
        if ((unsigned)((K) + base0) <= (unsigned)w0) sum0 += val; }

    STG(awx, awy, ash, aad, 0); ISS(aqA, aqB, aad);
    STG(bwx, bwy, bsh, bad, 1); ISS(bqA, bqB, bad);
    for (int k = 0; k < len; k += 2) {
        CNS(aqA, aqB, awx, awy, ash, k);
        STG(awx, awy, ash, aad, k + 2); ISS(aqA, aqB, aad);
        CNS(bqA, bqB, bwx, bwy, bsh, k + 1);
        STG(bwx, bwy, bsh, bad, k + 3); ISS(bqA, bqB, bad);
    }
    // drain outstanding junk reads before LDS is reused (WAW on dest VGPRs)
    asm volatile("s_waitcnt lgkmcnt(0)"
                 : "+v"(aqA), "+v"(aqB), "+v"(bqA), "+v"(bqB));

#undef STG
#undef ISS
#undef CNS

    // ---- reduce partials; reuse simg as scratch ----
    __syncthreads();
    float* red = (float*)simg;                 // 8 KB of 150 KB
    red[(0 * SPLIT + s) * W + c] = sum0;
    red[(1 * SPLIT + s) * W + c] = sum1;
    __syncthreads();

    if (s == 0) {
        const float acc0 = red[0 * W + c] + red[1 * W + c] + red[2 * W + c] + red[3 * W + c];
        const float* r1p = red + SPLIT * W;
        const float acc1 = r1p[0 * W + c] + r1p[1 * W + c] + r1p[2 * W + c] + r1p[3 * W + c];
        out[(((size_t)n * 2 + 0) * W + c) * NA + a] = acc0 * (1.0f / (float)(2 * t0));
        out[(((size_t)n * 2 + 1) * W + c) * NA + a] = acc1 * (1.0f / (float)(2 * t1));
    }
}

extern "C" void kernel_launch(void* const* d_in, const int* in_sizes, int n_in,
                              void* d_out, int out_size, void* d_ws, size_t ws_size,
                              hipStream_t stream) {
    const float* x = (const float*)d_in[0];
    const int* index_p = (const int*)d_in[1];
    float* out = (float*)d_out;
    const int N = in_sizes[0] / (W * W); // 4
    dim3 grid(NA, N);
    radon_kernel<<<grid, 1024, 0, stream>>>(x, index_p, out);
}

// Round 17
// 47.930 us; speedup vs baseline: 1.3854x; 1.0449x over previous
//
#include <hip/hip_runtime.h>
#include <hip/hip_fp16.h>

#define W 256
#define NA 180
#define SPLIT 4               // reduction slots (threads' s dimension)
#define ROWBYTES 580          // 290 halfs = 145 words; odd word stride -> axis walks spread over banks
#define ROWS 259              // data rows 1..256 (pixel y + 1); data cols (halfs) 2..257 (pixel x + 2)

__global__ __launch_bounds__(1024) void radon_kernel(
    const float* __restrict__ x, const int* __restrict__ index_p,
    float* __restrict__ out)
{
    __shared__ __half simg[ROWS * 290];   // 150,220 B

    const int a = blockIdx.x;        // angle 0..179
    const int n = blockIdx.y;        // batch
    const int tid = threadIdx.x;
    const int c = tid & (W - 1);     // column 0..255
    const int s = tid >> 8;          // 0..3 (wave-uniform)

    const float* __restrict__ img = x + (size_t)n * W * W;

    // ---- guard zero-fill (cells disjoint from staged data -> one barrier total) ----
    {
        unsigned* wp = (unsigned*)simg;
        if (tid < 435) {                       // rows 0,257,258: 3 x 145 words
            const int rr = tid / 145;
            const int w = tid - rr * 145;
            const int row = (rr == 0) ? 0 : (256 + rr);
            wp[row * 145 + w] = 0u;
        } else if (tid < 947) {                // col guard words 0,129 rows 1..256
            const int i = tid - 435;
            const int row = 1 + (i >> 1);
            const int w = (i & 1) ? 129 : 0;
            wp[row * 145 + w] = 0u;
        }
    }

    // ---- stage image -> LDS fp16 ----
    {
        const float4* img4 = (const float4*)img;
        #pragma unroll
        for (int k = 0; k < 16; ++k) {
            const int g = k * 1024 + tid;
            const int row = (g >> 6) + 1;      // 1..256
            const int m = g & 63;
            const float4 v = img4[g];
            const __half2 h01 = __floats2half2_rn(v.x, v.y);
            const __half2 h23 = __floats2half2_rn(v.z, v.w);
            char* base = (char*)simg + row * ROWBYTES + 8 * m + 4;  // halfs 4m+2..
            *(unsigned*)(base)     = *(const unsigned*)&h01;
            *(unsigned*)(base + 4) = *(const unsigned*)&h23;
        }
    }
    __syncthreads();

    const int index = *index_p;
    const int seg[6] = {1, 26, 51, 77, 102, 128};
    const int t0 = seg[4 - index];
    const int t1 = seg[4 - index + 1];

    float sa, ca;
    sincosf((float)a * 0.017453292519943295f, &sa, &ca);

    const float xc = ((2.0f * (float)c + 1.0f) * (1.0f / (float)W)) - 1.0f;
    const float bx = fmaf(128.0f * ca, xc, 127.5f + 2.0f);
    const float by = fmaf(-128.0f * sa, xc, 127.5f + 1.0f);

    const int r1lo = 128 - t1;
    const int r0lo = 128 - t0, r0hi = 127 + t0;
    const int w0 = r0hi - r0lo;            // inner-window width-1
    const int total = 2 * t1;

    // ---- 8 chunks; thread runs chunks s and s+4 as independent streams ----
    const int clo = total >> 3, rem = total & 7;
    const int sB = s + 4;
    const int LA = clo + (s  < rem);
    const int LB = clo + (sB < rem);
    const int startA = r1lo + s  * clo + min(s,  rem);
    const int startB = r1lo + sB * clo + min(sB, rem);
    const int common = LB;                 // LA >= LB, LA-LB in {0,1}

    const char* S = (const char*)simg;

#define TAP(RF, SUM0, SUM1, RI)                                               \
    {                                                                         \
        float ixf = fmaf(sa, RF, bx);                                         \
        float iyf = fmaf(ca, RF, by);                                         \
        ixf = __builtin_amdgcn_fmed3f(ixf, 1.0f, 258.0f);                     \
        iyf = __builtin_amdgcn_fmed3f(iyf, 0.0f, 257.0f);                     \
        const float wx = __builtin_amdgcn_fractf(ixf);                        \
        const float wy = __builtin_amdgcn_fractf(iyf);                        \
        const int x0 = (int)ixf;                                              \
        const int y0 = (int)iyf;                                              \
        const int sh = (x0 & 1) << 4;                                         \
        const char* p = S + (y0 * ROWBYTES + (x0 >> 1) * 4);                  \
        const unsigned A0 = *(const unsigned*)(p);                            \
        const unsigned A1 = *(const unsigned*)(p + ROWBYTES);                 \
        const unsigned B0 = *(const unsigned*)(p + 4);                        \
        const unsigned B1 = *(const unsigned*)(p + ROWBYTES + 4);             \
        const unsigned q0 = (unsigned)(((((unsigned long long)B0) << 32) | A0) >> sh); \
        const unsigned q1 = (unsigned)(((((unsigned long long)B1) << 32) | A1) >> sh); \
        const __half2 h0 = *(const __half2*)&q0;                              \
        const __half2 h1 = *(const __half2*)&q1;                              \
        const float v00 = __low2float(h0), v01 = __high2float(h0);            \
        const float v10 = __low2float(h1), v11 = __high2float(h1);            \
        const float top = fmaf(wx, v01 - v00, v00);                          \
        const float bot = fmaf(wx, v11 - v10, v10);                          \
        const float val = fmaf(wy, bot - top, top);                          \
        SUM1 += val;                                                          \
        if ((unsigned)((RI) - r0lo) <= (unsigned)w0) SUM0 += val;             \
    }

    float s0A = 0.0f, s1A = 0.0f, s0B = 0.0f, s1B = 0.0f;
    float rfA = (float)startA - 127.5f;
    float rfB = (float)startB - 127.5f;
    int   rA = startA, rB = startB;

    #pragma unroll 2
    for (int k = 0; k < common; ++k) {
        TAP(rfA, s0A, s1A, rA)
        TAP(rfB, s0B, s1B, rB)
        rfA += 1.0f; rfB += 1.0f; ++rA; ++rB;
    }
    if (LA > common) {                      // wave-uniform extra A tap
        TAP(rfA, s0A, s1A, rA)
    }
#undef TAP

    const float sum0 = s0A + s0B;
    const float sum1 = s1A + s1B;

    // ---- reduce partials; reuse simg as scratch ----
    __syncthreads();
    float* red = (float*)simg;                 // 8 KB of 150 KB
    red[(0 * SPLIT + s) * W + c] = sum0;
    red[(1 * SPLIT + s) * W + c] = sum1;
    __syncthreads();

    if (s == 0) {
        const float acc0 = red[0 * W + c] + red[1 * W + c] + red[2 * W + c] + red[3 * W + c];
        const float* r1p = red + SPLIT * W;
        const float acc1 = r1p[0 * W + c] + r1p[1 * W + c] + r1p[2 * W + c] + r1p[3 * W + c];
        out[(((size_t)n * 2 + 0) * W + c) * NA + a] = acc0 * (1.0f / (float)(2 * t0));
        out[(((size_t)n * 2 + 1) * W + c) * NA + a] = acc1 * (1.0f / (float)(2 * t1));
    }
}

extern "C" void kernel_launch(void* const* d_in, const int* in_sizes, int n_in,
                              void* d_out, int out_size, void* d_ws, size_t ws_size,
                              hipStream_t stream) {
    const float* x = (const float*)d_in[0];
    const int* index_p = (const int*)d_in[1];
    float* out = (float*)d_out;
    const int N = in_sizes[0] / (W * W); // 4
    dim3 grid(NA, N);
    radon_kernel<<<grid, 1024, 0, stream>>>(x, index_p, out);
}